// Round 18
// baseline (31.024 us; speedup 1.0000x reference)
//
#include <hip/hip_runtime.h>
#include <cstdint>

// D-FINE post-processor, SINGLE fused kernel: one block per batch (256 x 1024).
//   Filter: per-wave global_load_lds DMA pipeline (HBM -> LDS direct, no
//     VGPR-return path). QUAD-buffered 32 KB chunks (4 in flight, 8 KB/wave);
//     each wave DMAs and consumes ONLY its own 2 KB slice per chunk -> no
//     __syncthreads in the pipeline. Counted s_waitcnt vmcnt(6/4/2/0) +
//     sched_barrier(0) fences (rule #18: pin ds_reads behind the asm waitcnt).
//     Hits (logit > THR) compact into LDS cand[] via an LDS counter.
//     {x > THR} is a prefix of the descending order, so if K <= n <= CAPL the
//     top-K is provably contained.
//   Select (R10): rank-based selection (count-of-greater over packed
//     (key<<32)|~idx keys = exact jax.lax.top_k tie semantics, broadcast LDS
//     reads), scatter-emit by rank.
//   Fallback: exact histogram selection (hist/partial overlay the drained DMA
//     buffers) if the bound check fails.
// Output (float32): labels [B*K] | boxes [B*K*4] | scores [B*K]

constexpr int   NT     = 1024;
constexpr int   NBINS  = 4096;
constexpr int   CAPL   = 2048;   // LDS candidate capacity (~497 expected, 70 sigma)
constexpr int   CHUNK4 = 2048;   // float4s per DMA chunk (32 KB)
constexpr int   NBUF   = 4;      // quad buffer: 128 KB LDS, 8 KB in flight per wave
constexpr float THR    = 2.5f;   // static pre-filter (fallback makes it safe)

__device__ __forceinline__ unsigned f2key(float f) {
    unsigned u = __float_as_uint(f);
    return (u & 0x80000000u) ? ~u : (u | 0x80000000u);
}
__device__ __forceinline__ float key2f(unsigned k) {
    unsigned u = (k & 0x80000000u) ? (k & 0x7FFFFFFFu) : ~k;
    return __uint_as_float(u);
}
__device__ __forceinline__ unsigned long long packkv(unsigned key, unsigned idx) {
    return ((unsigned long long)key << 32) | (unsigned long long)(0xFFFFFFFFu - idx);
}

// HBM -> LDS direct DMA, 16 B per lane. LDS dest is wave-uniform base + lane*16;
// global src is per-lane. vmcnt-tracked, no VGPR writeback.
typedef const __attribute__((address_space(1))) unsigned g_u32;
typedef __attribute__((address_space(3))) unsigned l_u32;
__device__ __forceinline__ void gload_lds16(const void* g, void* l) {
    __builtin_amdgcn_global_load_lds((g_u32*)g, (l_u32*)l, 16, 0, 0);
}

__device__ __forceinline__ void consume1(
    float x, unsigned idx, unsigned* lcnt, unsigned long long* cand)
{
    if (x > THR) {
        unsigned p = atomicAdd(lcnt, 1u);
        if (p < (unsigned)CAPL) cand[p] = packkv(f2key(x), idx);
    }
}
__device__ __forceinline__ void consume4(
    float4 v, int i4, int N4, unsigned* lcnt, unsigned long long* cand)
{
    if (i4 < N4) {
        float mx = fmaxf(fmaxf(v.x, v.y), fmaxf(v.z, v.w));
        if (mx > THR) {
            unsigned bi = (unsigned)(4 * i4);
            consume1(v.x, bi + 0, lcnt, cand);
            consume1(v.y, bi + 1, lcnt, cand);
            consume1(v.z, bi + 2, lcnt, cand);
            consume1(v.w, bi + 3, lcnt, cand);
        }
    }
}

__global__ __launch_bounds__(NT) void dfine_fused_kernel(
    const float* __restrict__ logits,   // [B, Q*C]
    const float* __restrict__ pboxes,   // [B, Q, 4]  (cx, cy, w, h)
    const float* __restrict__ sizes,    // [B, 2]
    float* __restrict__ out,            // labels | boxes | scores
    int B, int Q, int C, int K)
{
    const int b   = blockIdx.x;
    const int tid = threadIdx.x;
    const int w   = tid >> 6;           // wave id (0..15)
    const int l   = tid & 63;           // lane id
    const int N   = Q * C;
    const int N4  = N >> 2;             // N divisible by 4 (C=80)
    const float4* __restrict__ base4 = reinterpret_cast<const float4*>(logits + (long long)b * N);

    __shared__ alignas(16) char dmabuf[NBUF][CHUNK4 * 16];  // 128 KB
    __shared__ unsigned long long cand[CAPL];               // 16 KB
    __shared__ unsigned lcnt;
    __shared__ unsigned candCount;
    __shared__ unsigned threshBin;

    if (tid == 0) lcnt = 0u;
    __syncthreads();

    // ---- filter: per-wave DMA pipeline, 4 chunks in flight, no barriers ----
    {
        const int NCH = (N4 + CHUNK4 - 1) / CHUNK4;         // 10 at N4=20000

        auto issue = [&](int c) {
            if (c >= NCH) return;
            char* lb = &dmabuf[c % NBUF][(w * 128) * 16];   // wave-uniform base
            int bi4 = c * CHUNK4 + w * 128;
            #pragma unroll
            for (int inst = 0; inst < 2; ++inst) {
                int i4 = bi4 + inst * 64 + l;
                gload_lds16(base4 + ((i4 < N4) ? i4 : (N4 - 1)), lb + inst * 1024);
            }
        };

        issue(0); issue(1); issue(2); issue(3);
        __builtin_amdgcn_sched_barrier(0);
        for (int c = 0; c < NCH; ++c) {
            // wait for chunk c's 2 DMAs; outstanding after = 2*(chunks still in flight)
            if (c + 3 < NCH)      asm volatile("s_waitcnt vmcnt(6)" ::: "memory");
            else if (c + 2 < NCH) asm volatile("s_waitcnt vmcnt(4)" ::: "memory");
            else if (c + 1 < NCH) asm volatile("s_waitcnt vmcnt(2)" ::: "memory");
            else                  asm volatile("s_waitcnt vmcnt(0)" ::: "memory");
            __builtin_amdgcn_sched_barrier(0);              // rule #18: pin ds_reads
            const char* lb = &dmabuf[c % NBUF][(w * 128) * 16];
            float4 v0 = *reinterpret_cast<const float4*>(lb + l * 16);
            float4 v1 = *reinterpret_cast<const float4*>(lb + (64 + l) * 16);
            int i40 = c * CHUNK4 + w * 128 + l;
            consume4(v0, i40,      N4, &lcnt, cand);
            consume4(v1, i40 + 64, N4, &lcnt, cand);
            __builtin_amdgcn_sched_barrier(0);              // consume before reuse
            issue(c + 4);                                   // buffer (c%NBUF) now free
            __builtin_amdgcn_sched_barrier(0);
        }
    }
    __syncthreads();

    int n;
    const unsigned tot = lcnt;
    if (tot >= (unsigned)K && tot <= (unsigned)CAPL) {
        n = (int)tot;                               // hot path: cand[] already in LDS
    } else {
        // ---- fallback: exact histogram selection (overlays drained DMA bufs) ----
        unsigned* hist    = reinterpret_cast<unsigned*>(&dmabuf[0][0]);   // 16 KB
        unsigned* partial = hist + NBINS;                                 //  4 KB
        const float* __restrict__ lg = logits + (long long)b * N;
        for (int i = tid; i < NBINS; i += NT) hist[i] = 0u;
        if (tid == 0) candCount = 0u;
        __syncthreads();
        for (int i = tid; i < N; i += NT)
            atomicAdd(&hist[f2key(lg[i]) >> 20], 1u);
        __syncthreads();
        {
            const int BPT = NBINS / NT;
            unsigned s = 0;
            #pragma unroll
            for (int m = 0; m < BPT; ++m) s += hist[tid * BPT + m];
            partial[tid] = s;
        }
        __syncthreads();
        if (tid < 64) {
            const int PPG = NT / 64;
            unsigned gs = 0;
            #pragma unroll
            for (int m = 0; m < PPG; ++m) gs += partial[tid * PPG + m];
            unsigned pre = gs;
            #pragma unroll
            for (int off = 1; off < 64; off <<= 1) {
                unsigned t = __shfl_up(pre, off);
                if (tid >= off) pre += t;
            }
            unsigned total = __shfl(pre, 63);
            unsigned suf   = total - (pre - gs);
            unsigned long long m1 = __ballot(suf >= (unsigned)K);
            int g = 63 - __clzll(m1);
            unsigned above = total - __shfl(pre, g);
            unsigned hv = hist[g * 64 + tid];
            unsigned pre2 = hv;
            #pragma unroll
            for (int off = 1; off < 64; off <<= 1) {
                unsigned t = __shfl_up(pre2, off);
                if (tid >= off) pre2 += t;
            }
            unsigned total2 = __shfl(pre2, 63);
            unsigned suf2   = above + total2 - (pre2 - hv);
            unsigned long long m2 = __ballot(suf2 >= (unsigned)K);
            int l2 = 63 - __clzll(m2);
            if (tid == 0) threshBin = (unsigned)(g * 64 + l2);
        }
        __syncthreads();
        const unsigned tb = threshBin;
        for (int i = tid; i < N; i += NT) {
            unsigned k = f2key(lg[i]);
            if ((k >> 20) >= tb) {
                unsigned p = atomicAdd(&candCount, 1u);
                if (p < (unsigned)CAPL) cand[p] = packkv(k, (unsigned)i);
            }
        }
        __syncthreads();
        n = (int)min(candCount, (unsigned)CAPL);
    }

    // ---- rank-based selection + emit ----
    const int BK = B * K;
    float* __restrict__ out_labels = out;
    float* __restrict__ out_boxes  = out + BK;
    float* __restrict__ out_scores = out + (long long)BK * 5;
    const float s0 = sizes[2 * b];
    const float s1 = sizes[2 * b + 1];

    for (int t = tid; t < n; t += NT) {
        unsigned long long my = cand[t];
        int r = 0;
        for (int j = 0; j < n; ++j) r += (cand[j] > my);   // packed keys unique
        if (r < K) {
            unsigned key = (unsigned)(my >> 32);
            unsigned idx = 0xFFFFFFFFu - (unsigned)(my & 0xFFFFFFFFull);
            float logit = key2f(key);
            float score = 1.0f / (1.0f + expf(-logit));
            int label = (int)(idx % (unsigned)C);
            int q     = (int)(idx / (unsigned)C);
            float4 bp = *reinterpret_cast<const float4*>(pboxes + ((long long)b * Q + q) * 4);
            int o = b * K + r;
            out_labels[o] = (float)label;
            out_scores[o] = score;
            float4 bb;
            bb.x = (bp.x - 0.5f * bp.z) * s0;
            bb.y = (bp.y - 0.5f * bp.w) * s1;
            bb.z = (bp.x + 0.5f * bp.z) * s0;
            bb.w = (bp.y + 0.5f * bp.w) * s1;
            *reinterpret_cast<float4*>(out_boxes + 4LL * o) = bb;
        }
    }
}

extern "C" void kernel_launch(void* const* d_in, const int* in_sizes, int n_in,
                              void* d_out, int out_size, void* d_ws, size_t ws_size,
                              hipStream_t stream) {
    const float* logits = (const float*)d_in[0];
    const float* pboxes = (const float*)d_in[1];
    const float* sizes  = (const float*)d_in[2];

    const int B = in_sizes[2] / 2;                 // 256
    const int Q = in_sizes[1] / (4 * B);           // 1000
    const int C = in_sizes[0] / (B * Q);           // 80
    const int K = out_size / (6 * B);              // 300

    dfine_fused_kernel<<<B, NT, 0, stream>>>(
        logits, pboxes, sizes, (float*)d_out, B, Q, C, K);
}